// Round 3
// baseline (124.495 us; speedup 1.0000x reference)
//
#include <hip/hip_runtime.h>
#include <cstdint>

// VQ-VAE vector quantizer, MI355X (gfx950). Round 8.
// Evidence r7: sync-free reg-dbuf structure landed ~40us (inferred: total-main
// offset ~73.5us stable across r0/r1). Remaining theory: B-traffic 512MB L2
// (14.8us floor) x thin prefetch (1 slice ~350cyc vs L2 lat ~300cyc, 2 waves/
// SIMD) -> per-slice stalls. r8 keeps zero in-loop coupling and:
//  - wave = 2 row-tiles (32 rows) x HALF codebook (8 slices): B 128KB/wave ->
//    256MB L2 total (7.4us). Halves merged ONCE at end via LDS (3 barriers
//    total, none in loop).
//  - packed A shared via LDS (4KB/tile, 1 publish barrier): z read once.
//  - 64 MFMA + 128 VALU per 16-load slice (~1300cyc) >> L2 latency: depth-1
//    dbuf suffices.
//  - nontemporal z loads + out stores: streams can't evict emb8 from L2.
// Floors: MFMA 8.4us, L2-B 7.4us, issue ~3.5us -> predict main 14-18us.
// Discriminator: if total ~110+ again, wall is environmental (clocks) ->
// instrument s_memtime next, stop restructuring.

typedef float f32x4 __attribute__((ext_vector_type(4)));
typedef long  l2    __attribute__((ext_vector_type(2)));
typedef _Float16 f16;
typedef f16 f16x8 __attribute__((ext_vector_type(8)));

#define D_DIM 256
#define K_CODES 1024

__device__ __forceinline__ long pack_fp8x8(float x0, float x1, float x2, float x3,
                                           float x4, float x5, float x6, float x7) {
    int w0 = __builtin_amdgcn_cvt_pk_fp8_f32(x0, x1, 0, false);
    w0     = __builtin_amdgcn_cvt_pk_fp8_f32(x2, x3, w0, true);
    int w1 = __builtin_amdgcn_cvt_pk_fp8_f32(x4, x5, 0, false);
    w1     = __builtin_amdgcn_cvt_pk_fp8_f32(x6, x7, w1, true);
    int2 p = {w0, w1};
    return __builtin_bit_cast(long, p);
}

// ---- Prep (verified r5-r7, unchanged): zero loss slot; emb -> fp8 (x1024) in
// fragment-slice-linear order (16 slices of 64 codes; chunk = ct*256 + t*64 +
// q*16 + m holds k-dims [t*64+q*8,+8) and [t*64+32+q*8,+8) of code
// sp*64+ct*16+m); eTe = 1024*||e||^2 fp32. grid 256 x 256.
__global__ __launch_bounds__(256) void vq_prep(const float* __restrict__ emb,
                                               char* __restrict__ emb8,
                                               float* __restrict__ eTe,
                                               float* __restrict__ loss_slot) {
    const int tid = threadIdx.x, wave = tid >> 6, lane = tid & 63;
    if (blockIdx.x == 0 && tid == 0) *loss_slot = 0.0f;

    if (blockIdx.x < 64) {
        int ch  = blockIdx.x * 256 + tid;     // 16384 chunks
        int sp  = ch >> 10;
        int rem = ch & 1023;
        int ct  = rem >> 8;
        int t   = (rem >> 6) & 3;
        int l   = rem & 63;
        int qq  = l >> 4, mm = l & 15;
        int code = sp * 64 + ct * 16 + mm;
        const float* p = emb + (size_t)code * D_DIM;
        int b0 = t * 64 + qq * 8;
        int b1 = b0 + 32;
        float4 v0 = *(const float4*)(p + b0);
        float4 v1 = *(const float4*)(p + b0 + 4);
        float4 v2 = *(const float4*)(p + b1);
        float4 v3 = *(const float4*)(p + b1 + 4);
        l2 out;
        out.x = pack_fp8x8(v0.x * 1024.f, v0.y * 1024.f, v0.z * 1024.f, v0.w * 1024.f,
                           v1.x * 1024.f, v1.y * 1024.f, v1.z * 1024.f, v1.w * 1024.f);
        out.y = pack_fp8x8(v2.x * 1024.f, v2.y * 1024.f, v2.z * 1024.f, v2.w * 1024.f,
                           v3.x * 1024.f, v3.y * 1024.f, v3.z * 1024.f, v3.w * 1024.f);
        *(l2*)(emb8 + (size_t)ch * 16) = out;
    }

    // eTe: one wave per code, 4 codes per block, pre-scaled by 1024.
    int code = blockIdx.x * 4 + wave;
    float4 v = ((const float4*)(emb + (size_t)code * D_DIM))[lane];
    float s = v.x * v.x + v.y * v.y + v.z * v.z + v.w * v.w;
    #pragma unroll
    for (int off = 32; off >= 1; off >>= 1) s += __shfl_down(s, off);
    if (lane == 0) eTe[code] = 1024.0f * s;
}

// ---- Main kernel -----------------------------------------------------------
__device__ __forceinline__ void loadB(l2 (&B)[16], const l2* __restrict__ gB,
                                      int sl, int lane) {
    const l2* p = gB + (size_t)sl * 1024 + lane;
    #pragma unroll
    for (int j = 0; j < 16; j++) B[j] = p[j * 64];   // 1KB coalesced each
}

// Score one 64-code slice against TWO row-tiles (Aa, Ab). 64 MFMAs in 8
// independent chains; selects stay in-lane.
__device__ __forceinline__ void computeSlice2(const l2 (&B)[16],
                                              const long (&Aa)[8], const long (&Ab)[8],
                                              const float* __restrict__ eTe, int code0,
                                              int m, float (&best)[2][4], int (&bidx)[2][4]) {
    float ete[4];
    #pragma unroll
    for (int ct = 0; ct < 4; ct++) ete[ct] = eTe[code0 + ct * 16 + m];

    f32x4 acc[2][4];
    #pragma unroll
    for (int j = 0; j < 2; j++)
        #pragma unroll
        for (int ct = 0; ct < 4; ct++) acc[j][ct] = (f32x4){0.f, 0.f, 0.f, 0.f};

    __builtin_amdgcn_s_setprio(1);
    #pragma unroll
    for (int t = 0; t < 4; t++) {
        #pragma unroll
        for (int ct = 0; ct < 4; ct++) {
            acc[0][ct] = __builtin_amdgcn_mfma_f32_16x16x32_fp8_fp8(Aa[2*t],   B[ct*4+t].x, acc[0][ct], 0, 0, 0);
            acc[1][ct] = __builtin_amdgcn_mfma_f32_16x16x32_fp8_fp8(Ab[2*t],   B[ct*4+t].x, acc[1][ct], 0, 0, 0);
            acc[0][ct] = __builtin_amdgcn_mfma_f32_16x16x32_fp8_fp8(Aa[2*t+1], B[ct*4+t].y, acc[0][ct], 0, 0, 0);
            acc[1][ct] = __builtin_amdgcn_mfma_f32_16x16x32_fp8_fp8(Ab[2*t+1], B[ct*4+t].y, acc[1][ct], 0, 0, 0);
        }
    }
    __builtin_amdgcn_s_setprio(0);

    #pragma unroll
    for (int ct = 0; ct < 4; ct++) {
        const int code = code0 + ct * 16 + m;
        #pragma unroll
        for (int j = 0; j < 2; j++)
            #pragma unroll
            for (int r = 0; r < 4; r++) {
                float sc = fmaf(-2.0f, acc[j][ct][r], ete[ct]);
                if (sc < best[j][r]) { best[j][r] = sc; bidx[j][r] = code; }
            }
    }
}

// Block = 4 waves x 64 rows (4 tiles of 16). Wave v: tiles {(v&1)*2, +1},
// code-half v>>1. Wave v packs tile v to fp8, publishes via LDS (1 barrier).
// In-loop: zero barriers / shuffles / LDS. End: per-(tile,half) argmin to LDS,
// 1 barrier, wave w merges + gathers + writes tile w's 16 rows.
__global__ __launch_bounds__(256, 2) void vq_main5(const float* __restrict__ z,
                                                   const char* __restrict__ emb8,
                                                   const float* __restrict__ eTe,
                                                   const float* __restrict__ emb,
                                                   float* __restrict__ out,
                                                   float* __restrict__ loss_slot,
                                                   float loss_scale) {
    __shared__ long  s_a8[4][8][64];     // 16 KB packed-A publish
    __shared__ float s_b[4][2][16];      // [tile][half][row] best
    __shared__ int   s_i[4][2][16];
    __shared__ float s_red[4];

    const int tid  = threadIdx.x;
    const int w    = tid >> 6;         // wave 0..3
    const int lane = tid & 63;
    const int m    = lane & 15;        // A row / B col (code) / C col
    const int q    = lane >> 4;        // k-group / C row-group
    const int hb   = w >> 1;           // code half (0: codes 0-511)
    const int tA   = (w & 1) * 2;      // tiles this wave scores
    const int tB   = tA + 1;

    const l2* gB = (const l2*)emb8 + (size_t)(hb * 8) * 1024;
    l2 Ba[16], Bb[16];
    loadB(Ba, gB, 0, lane);            // slice 0 in flight under A-pack

    // Pack OWN tile w (rows blockIdx*64 + w*16 ..): lane (q,m) holds row m,
    // k-dims [s*32+q*8,+8) per k-step s (verified r5-r7 layout). nt loads.
    float zsq = 0.f;
    {
        const f32x4* zr = (const f32x4*)(z + ((size_t)blockIdx.x * 64 + w * 16 + m) * D_DIM);
        long A8o[8];
        #pragma unroll
        for (int s = 0; s < 8; s++) {
            f32x4 v0 = __builtin_nontemporal_load(zr + s * 8 + q * 2);
            f32x4 v1 = __builtin_nontemporal_load(zr + s * 8 + q * 2 + 1);
            zsq += v0[0]*v0[0] + v0[1]*v0[1] + v0[2]*v0[2] + v0[3]*v0[3]
                 + v1[0]*v1[0] + v1[1]*v1[1] + v1[2]*v1[2] + v1[3]*v1[3];
            A8o[s] = pack_fp8x8(v0[0], v0[1], v0[2], v0[3], v1[0], v1[1], v1[2], v1[3]);
        }
        #pragma unroll
        for (int s = 0; s < 8; s++) s_a8[w][s][lane] = A8o[s];
    }
    __syncthreads();                   // publish packed A (drains Ba too)

    loadB(Bb, gB, 1, lane);            // slice 1 overlaps slice-0 compute
    long A8a[8], A8b[8];
    #pragma unroll
    for (int s = 0; s < 8; s++) { A8a[s] = s_a8[tA][s][lane]; A8b[s] = s_a8[tB][s][lane]; }

    float best[2][4];
    int   bidx[2][4];
    #pragma unroll
    for (int j = 0; j < 2; j++)
        #pragma unroll
        for (int r = 0; r < 4; r++) { best[j][r] = __builtin_inff(); bidx[j][r] = 0; }

    const int codeH = hb * 512;
    #pragma unroll 1
    for (int ii = 0; ii < 8; ii += 2) {
        computeSlice2(Ba, A8a, A8b, eTe, codeH + ii * 64, m, best, bidx);
        if (ii + 2 < 8) loadB(Ba, gB, ii + 2, lane);
        computeSlice2(Bb, A8a, A8b, eTe, codeH + (ii + 1) * 64, m, best, bidx);
        if (ii + 3 < 8) loadB(Bb, gB, ii + 3, lane);
    }

    // Per-(tile,half) argmin: one butterfly set per wave, results to LDS.
    #pragma unroll
    for (int j = 0; j < 2; j++)
        #pragma unroll
        for (int r = 0; r < 4; r++) {
            float b  = best[j][r];
            int   bi = bidx[j][r];
            #pragma unroll
            for (int off = 8; off >= 1; off >>= 1) {
                float ob = __shfl_xor(b, off);
                int   oi = __shfl_xor(bi, off);
                if (ob < b || (ob == b && oi < bi)) { b = ob; bi = oi; }
            }
            if (m == 0) {
                s_b[tA + j][hb][q * 4 + r] = b;
                s_i[tA + j][hb][q * 4 + r] = bi;
            }
        }
    __syncthreads();

    // Wave w merges halves + gathers + writes its packed tile w's 16 rows.
    // half0 wins ties (codes 0-511 < 512-1023 -> first-index semantics).
    float lsum = 0.f;
    {
        float* orow = out + ((size_t)blockIdx.x * 64 + w * 16) * D_DIM + (size_t)lane * 4;
        #pragma unroll
        for (int row = 0; row < 16; row++) {
            float b0 = s_b[w][0][row], b1 = s_b[w][1][row];
            int   i0 = s_i[w][0][row], i1 = s_i[w][1][row];
            bool take1 = (b1 < b0);
            int   bi = take1 ? i1 : i0;
            lsum += take1 ? b1 : b0;
            f32x4 ev = *(const f32x4*)(emb + (size_t)bi * D_DIM + lane * 4);
            __builtin_nontemporal_store(ev, (f32x4*)(orow + (size_t)row * D_DIM));
        }
    }

    // loss: zsq covers tile w (packed once per wave), lsum covers tile w.
    #pragma unroll
    for (int off = 32; off >= 1; off >>= 1) zsq += __shfl_down(zsq, off);
    if (lane == 0) s_red[w] = zsq + lsum * (1.0f / 1024.0f);
    __syncthreads();
    if (tid == 0)
        atomicAdd(loss_slot, (s_red[0] + s_red[1] + s_red[2] + s_red[3]) * loss_scale);
}

// ---- Fallback (round-2 structure, verified) — only if ws too small. --------
__global__ __launch_bounds__(256) void vq_prep_fb(const float* __restrict__ emb,
                                                  float* __restrict__ eTe,
                                                  float* __restrict__ loss_slot) {
    if (blockIdx.x == 0 && threadIdx.x == 0) *loss_slot = 0.0f;
    if (!eTe) return;
    int gtid = blockIdx.x * 256 + threadIdx.x;
    int code = gtid >> 6;
    int lane = threadIdx.x & 63;
    if (code >= K_CODES) return;
    float4 v = ((const float4*)(emb + (size_t)code * D_DIM))[lane];
    float s = v.x * v.x + v.y * v.y + v.z * v.z + v.w * v.w;
    #pragma unroll
    for (int off = 32; off >= 1; off >>= 1) s += __shfl_down(s, off);
    if (lane == 0) eTe[code] = s;
}

__global__ __launch_bounds__(128) void vq_main_fb(const float* __restrict__ z,
                                                  const float* __restrict__ emb,
                                                  const float* __restrict__ eTe_g,
                                                  float* __restrict__ out,
                                                  float* __restrict__ loss_slot,
                                                  float loss_scale) {
    __shared__ __align__(16) f16 sE[128 * D_DIM];
    __shared__ float s_ete[128];
    __shared__ int   s_idx2[128];
    __shared__ float s_red2[2];

    const int tid  = threadIdx.x;
    const int wave = tid >> 6;
    const int lane = tid & 63;
    const int m    = lane & 15;
    const int q    = lane >> 4;
    const size_t row0 = (size_t)blockIdx.x * 128 + (size_t)wave * 64;

    f16x8 A[4][8];
    #pragma unroll
    for (int st = 0; st < 4; st++) {
        const float* zr = z + (row0 + st * 16 + m) * D_DIM;
        #pragma unroll
        for (int s = 0; s < 8; s++) {
            const float* p = zr + s * 32 + q * 8;
            float4 v0 = *(const float4*)p;
            float4 v1 = *(const float4*)(p + 4);
            f16x8 a = {(f16)v0.x, (f16)v0.y, (f16)v0.z, (f16)v0.w,
                       (f16)v1.x, (f16)v1.y, (f16)v1.z, (f16)v1.w};
            A[st][s] = a;
        }
    }
    float best[4][4]; int bidx[4][4];
    #pragma unroll
    for (int st = 0; st < 4; st++)
        #pragma unroll
        for (int r = 0; r < 4; r++) { best[st][r] = __builtin_inff(); bidx[st][r] = 0; }

    const f16x8* sE8 = (const f16x8*)sE;
    #pragma unroll 1
    for (int sp = 0; sp < 8; sp++) {
        __syncthreads();
        if (eTe_g) s_ete[tid] = 1024.0f * eTe_g[sp * 128 + tid];
        else {
            const float* p = emb + (size_t)(sp * 128 + tid) * D_DIM;
            float ss = 0.f;
            for (int j = 0; j < D_DIM / 4; j++) {
                float4 v = ((const float4*)p)[j];
                ss += v.x * v.x + v.y * v.y + v.z * v.z + v.w * v.w;
            }
            s_ete[tid] = 1024.0f * ss;
        }
        const float* ebase = emb + (size_t)sp * 128 * D_DIM;
        #pragma unroll 4
        for (int it = 0; it < 32; it++) {
            int ch = it * 128 + tid;
            int cc = ((ch >> 9) << 4) | (ch & 15);
            int gg = (ch >> 4) & 31;
            const float* p = ebase + cc * D_DIM + gg * 8;
            float4 v0 = *(const float4*)p;
            float4 v1 = *(const float4*)(p + 4);
            f16x8 h = {(f16)(v0.x * 1024.f), (f16)(v0.y * 1024.f),
                       (f16)(v0.z * 1024.f), (f16)(v0.w * 1024.f),
                       (f16)(v1.x * 1024.f), (f16)(v1.y * 1024.f),
                       (f16)(v1.z * 1024.f), (f16)(v1.w * 1024.f)};
            *(f16x8*)(sE + (size_t)ch * 8) = h;
        }
        __syncthreads();
        for (int ct = 0; ct < 8; ct++) {
            f32x4 acc[4];
            #pragma unroll
            for (int st = 0; st < 4; st++) acc[st] = (f32x4){0.f, 0.f, 0.f, 0.f};
            #pragma unroll
            for (int s = 0; s < 8; s++) {
                f16x8 bh = sE8[ct * 512 + s * 64 + lane];
                #pragma unroll
                for (int st = 0; st < 4; st++)
                    acc[st] = __builtin_amdgcn_mfma_f32_16x16x32_f16(A[st][s], bh, acc[st], 0, 0, 0);
            }
            int codeL = ct * 16 + m;
            float ete = s_ete[codeL];
            int code  = sp * 128 + codeL;
            #pragma unroll
            for (int st = 0; st < 4; st++)
                #pragma unroll
                for (int r = 0; r < 4; r++) {
                    float sc = fmaf(-2.0f, acc[st][r], ete);
                    if (sc < best[st][r]) { best[st][r] = sc; bidx[st][r] = code; }
                }
        }
    }
    #pragma unroll
    for (int st = 0; st < 4; st++)
        #pragma unroll
        for (int r = 0; r < 4; r++) {
            float b = best[st][r]; int bi = bidx[st][r];
            #pragma unroll
            for (int off = 8; off >= 1; off >>= 1) {
                float ob = __shfl_xor(b, off);
                int   oi = __shfl_xor(bi, off);
                if (ob < b || (ob == b && oi < bi)) { b = ob; bi = oi; }
            }
            if (m == 0) s_idx2[wave * 64 + st * 16 + q * 4 + r] = bi;
        }
    __syncthreads();
    float lsum = 0.f;
    #pragma unroll
    for (int st = 0; st < 4; st++) {
        int rl = wave * 64 + st * 16 + m;
        int idxv = s_idx2[rl];
        const float* er = emb + (size_t)idxv * D_DIM;
        float* orow = out + ((size_t)blockIdx.x * 128 + rl) * D_DIM;
        #pragma unroll
        for (int s = 0; s < 8; s++) {
            int dd = s * 32 + q * 8;
            float4 e0 = *(const float4*)(er + dd);
            float4 e1 = *(const float4*)(er + dd + 4);
            *(float4*)(orow + dd)     = e0;
            *(float4*)(orow + dd + 4) = e1;
            f16x8 a = A[st][s];
            float d0 = e0.x - (float)a[0], d1 = e0.y - (float)a[1];
            float d2 = e0.z - (float)a[2], d3 = e0.w - (float)a[3];
            float d4 = e1.x - (float)a[4], d5 = e1.y - (float)a[5];
            float d6 = e1.z - (float)a[6], d7 = e1.w - (float)a[7];
            lsum += d0*d0 + d1*d1 + d2*d2 + d3*d3 + d4*d4 + d5*d5 + d6*d6 + d7*d7;
        }
    }
    #pragma unroll
    for (int off = 32; off >= 1; off >>= 1) lsum += __shfl_down(lsum, off);
    if (lane == 0) s_red2[wave] = lsum;
    __syncthreads();
    if (tid == 0) atomicAdd(loss_slot, (s_red2[0] + s_red2[1]) * loss_scale);
}

extern "C" void kernel_launch(void* const* d_in, const int* in_sizes, int n_in,
                              void* d_out, int out_size, void* d_ws, size_t ws_size,
                              hipStream_t stream) {
    const float* z   = (const float*)d_in[0];
    const float* emb = (const float*)d_in[1];
    float* out = (float*)d_out;
    const int NROWS = in_sizes[0] / D_DIM;              // 32768
    float* loss_slot = out + (size_t)in_sizes[0];
    float loss_scale = 1.25f / (float)in_sizes[0];

    const size_t emb8_bytes = (size_t)K_CODES * D_DIM;  // 256 KB
    const size_t need = emb8_bytes + K_CODES * sizeof(float);

    if (ws_size >= need) {
        char*  emb8 = (char*)d_ws;
        float* eTe  = (float*)((char*)d_ws + emb8_bytes);
        vq_prep<<<256, 256, 0, stream>>>(emb, emb8, eTe, loss_slot);
        vq_main5<<<NROWS / 64, 256, 0, stream>>>(z, emb8, eTe, emb, out, loss_slot, loss_scale);
    } else {
        float* eTe = (ws_size >= K_CODES * sizeof(float)) ? (float*)d_ws : nullptr;
        vq_prep_fb<<<K_CODES / 4, 256, 0, stream>>>(emb, eTe, loss_slot);
        vq_main_fb<<<NROWS / 128, 128, 0, stream>>>(z, emb, eTe, out, loss_slot, loss_scale);
    }
}